// Round 9
// baseline (13985.718 us; speedup 1.0000x reference)
//
#include <hip/hip_runtime.h>
#include <utility>

#define TT 800
#define BB 128
#define HH 256
#define UU 64
#define AA 64
#define KK 10
#define GG 20
#define NWG 256
#define GB 32          // batches per group
#define NGRP 4

typedef float f32x4 __attribute__((ext_vector_type(4)));
typedef __bf16 bf16y8 __attribute__((ext_vector_type(8)));
typedef short bf16s8 __attribute__((ext_vector_type(8)));
typedef unsigned long long u64x2 __attribute__((ext_vector_type(2)));

__device__ __forceinline__ float bf2f(unsigned short u) {
  return __uint_as_float(((unsigned int)u) << 16);
}
__device__ __forceinline__ unsigned short f2bf(float f) {
  unsigned int x = __float_as_uint(f);
  x += 0x7FFFu + ((x >> 16) & 1u);
  return (unsigned short)(x >> 16);
}
__device__ __forceinline__ unsigned packf(float v) {
  unsigned short hi = f2bf(v);
  unsigned short lo = f2bf(v - bf2f(hi));
  return (unsigned)hi | ((unsigned)lo << 16);
}
__device__ __forceinline__ float unpackf(unsigned u) {
  return bf2f((unsigned short)(u & 0xFFFF)) + bf2f((unsigned short)(u >> 16));
}
__device__ __forceinline__ float sigm(float x) { return 1.0f / (1.0f + __expf(-x)); }
__device__ __forceinline__ float rin(const void* p, size_t i, bool f32) {
  return f32 ? ((const float*)p)[i] : bf2f(((const unsigned short*)p)[i]);
}
__device__ __forceinline__ bf16y8 ld8(const unsigned short* p) {
  return __builtin_bit_cast(bf16y8, *(const bf16s8*)p);
}

// agent-scope relaxed atomics for flag stores / state stores
__device__ __forceinline__ unsigned ald(const unsigned* p) {
  return __hip_atomic_load(p, __ATOMIC_RELAXED, __HIP_MEMORY_SCOPE_AGENT);
}
__device__ __forceinline__ void ast(unsigned* p, unsigned v) {
  __hip_atomic_store(p, v, __ATOMIC_RELAXED, __HIP_MEMORY_SCOPE_AGENT);
}

// Coherent 16B read (normal read path, full pipelining, bypasses stale caches).
// NOTE: no completion wait inside — pair with waitvm<N>() before consuming.
__device__ __forceinline__ void ld16(u64x2& d, const unsigned* p) {
  asm volatile("global_load_dwordx4 %0, %1, off sc0 sc1" : "=v"(d) : "v"(p));
}
// Counted vmem wait + scheduler fence (rule #18: keep consumers below the wait).
template <int N>
__device__ __forceinline__ void waitvm() {
  asm volatile("s_waitcnt vmcnt(%0)" :: "i"(N) : "memory");
  __builtin_amdgcn_sched_barrier(0);
}
// intra-wave LDS producer->consumer fence (other waves run concurrently)
__device__ __forceinline__ void wfence() {
  __builtin_amdgcn_sched_barrier(0);
  asm volatile("s_waitcnt lgkmcnt(0)" ::: "memory");
  __builtin_amdgcn_sched_barrier(0);
}
// wave-local drain of own global stores (w -> aflag ordering)
__device__ __forceinline__ void vdrain() {
  __builtin_amdgcn_sched_barrier(0);
  asm volatile("s_waitcnt vmcnt(0)" ::: "memory");
  __builtin_amdgcn_sched_barrier(0);
}

template <typename F, int... I>
__device__ __forceinline__ void unroll_seq(F&& f, std::integer_sequence<int, I...>) {
  (f(std::integral_constant<int, I>{}), ...);
}

// State planes are k-major: plane[kblk][b][j], kblk=hu>>3, j=hu&7.
// Flat: kblk*1024 + b*8 + j  (1024 = BB*8). 32B per (kblk,b): one dwordx4 pair.

struct KArgs {
  const void* in[27];
  float* out;
  float* kappa;
  unsigned *xu;               // packed x, [t][b][3], 307200
  unsigned *wu;               // packed w, k-major, 2 planes of 8192
  unsigned *h1[2], *h2[2], *h3[2];  // packed h planes, k-major, 32768 each
  unsigned* bar;              // [0] full cnt; [160..167] zero line; [256+] bflags; [256+8192+] aflags
};

// LDS B-fragment fill, hi/lo planes
__device__ void fillB(unsigned short* Bhi, unsigned short* Blo, const void* Wih,
                      const void* Whh, int KP, int ihCols, int ihEnd, int hhStart,
                      int q, int tid, bool f32) {
  int total = KP * 16;
  for (int idx = tid; idx < total; idx += 256) {
    int k = idx >> 4, n = idx & 15;
    int row = (n >> 2) * HH + q * 4 + (n & 3);
    float v = 0.f;
    if (k < 3) v = rin(Wih, (size_t)row * ihCols + k, f32);
    else if (k >= 8 && k < ihEnd) v = rin(Wih, (size_t)row * ihCols + (k - 5), f32);
    else if (k >= hhStart && k < hhStart + 256) v = rin(Whh, (size_t)row * HH + (k - hhStart), f32);
    unsigned short hi = f2bf(v);
    int a = ((k >> 3) * 16 + n) * 8 + (k & 7);
    Bhi[a] = hi;
    Blo[a] = f2bf(v - bf2f(hi));
  }
}

// MFMA hi/lo gate stage on wave pair {WB, WB+1} covering the group's 32 batches.
// A regions: kc0/quad0 -> x(3), [8,72) -> w, [72,328) -> r2, [328,584) -> r3.
// Loads: 2x dwordx4 sc0sc1 per kc, DEP deep, counted vmcnt (never 0 mid-loop).
template <int KC, bool R3, int WB>
__device__ __forceinline__ void gate_mfma(
    const unsigned* __restrict__ xt, const unsigned* __restrict__ wu,
    const unsigned* __restrict__ r2, const unsigned* __restrict__ r3,
    const unsigned* __restrict__ dz,
    const unsigned short* __restrict__ Bhi, const unsigned short* __restrict__ Blo,
    const float* __restrict__ bias4, float& creg, unsigned* __restrict__ hout,
    int grp, int q, float* zls, int tid) {
  const int wave = tid >> 6, lane = tid & 63;
  if ((wave >> 1) != (WB >> 1)) return;   // only waves WB, WB+1 participate
  const int wv = wave & 1;
  const int n15 = lane & 15, quad = lane >> 4;
  const int b = grp * GB + wv * 16 + n15;

  // x: plain cached loads (write-once data). Keep-alive use forces the
  // compiler's waitcnt for these HERE, before the counted-asm region.
  unsigned xv0 = 0, xv1 = 0, xv2 = 0;
  if (quad == 0) {
    xv0 = xt[b * 3 + 0];
    xv1 = xt[b * 3 + 1];
    xv2 = xt[b * 3 + 2];
  }
  asm volatile("" :: "v"(xv0), "v"(xv1), "v"(xv2));

  constexpr int DEP = 12;
  u64x2 buf[DEP][2];

  auto addr = [&](int kc) -> const unsigned* {
    const int k0 = kc * 32 + quad * 8;
    if (kc == 0 && quad == 0) return dz;
    if (k0 < 72) return wu + ((k0 - 8) >> 3) * 1024 + b * 8;
    if (k0 < 328) return r2 + ((k0 - 72) >> 3) * 1024 + b * 8;
    if (R3 && k0 < 584) return r3 + ((k0 - 328) >> 3) * 1024 + b * 8;
    return dz;   // zero line: same math as zero-fill, static load count
  };
  auto issue = [&](int kc, int slot) {
    const unsigned* p = addr(kc);
    ld16(buf[slot][0], p);
    ld16(buf[slot][1], p + 4);
  };

#pragma unroll
  for (int kc = 0; kc < DEP && kc < KC; ++kc) issue(kc, kc);

  f32x4 acc = {0.f, 0.f, 0.f, 0.f};

  unroll_seq([&](auto kcc) {
    constexpr int kc = decltype(kcc)::value;
    constexpr int end = (kc + DEP < KC) ? (kc + DEP) : KC;
    waitvm<2 * (end - kc - 1)>();          // kc's 2 loads complete; rest in flight
    u64x2* sp = buf[kc % DEP];
    unsigned long long s[4] = { sp[0][0], sp[0][1], sp[1][0], sp[1][1] };
    bf16s8 th, tl;
#pragma unroll
    for (int j = 0; j < 4; ++j) {
      unsigned lo32 = (unsigned)s[j], hi32 = (unsigned)(s[j] >> 32);
      th[2 * j] = (short)(lo32 & 0xFFFFu);     tl[2 * j] = (short)(lo32 >> 16);
      th[2 * j + 1] = (short)(hi32 & 0xFFFFu); tl[2 * j + 1] = (short)(hi32 >> 16);
    }
    if constexpr (kc == 0) {
      if (quad == 0) {
        th[0] = (short)(xv0 & 0xFFFFu); tl[0] = (short)(xv0 >> 16);
        th[1] = (short)(xv1 & 0xFFFFu); tl[1] = (short)(xv1 >> 16);
        th[2] = (short)(xv2 & 0xFFFFu); tl[2] = (short)(xv2 >> 16);
      }
    }
    bf16y8 ah = __builtin_bit_cast(bf16y8, th);
    bf16y8 al = __builtin_bit_cast(bf16y8, tl);
    const int boff = ((kc * 4 + quad) * 16 + n15) * 8;
    bf16y8 bh = ld8(Bhi + boff), bl = ld8(Blo + boff);
    acc = __builtin_amdgcn_mfma_f32_16x16x32_bf16(ah, bh, acc, 0, 0, 0);
    acc = __builtin_amdgcn_mfma_f32_16x16x32_bf16(ah, bl, acc, 0, 0, 0);
    acc = __builtin_amdgcn_mfma_f32_16x16x32_bf16(al, bh, acc, 0, 0, 0);
    if constexpr (kc + DEP < KC) issue(kc + DEP, kc % DEP);
  }, std::make_integer_sequence<int, KC>{});

  // wave-private LDS transpose
  float* zw = zls + wave * (16 * 17);
#pragma unroll
  for (int r = 0; r < 4; ++r) zw[(quad * 4 + r) * 17 + n15] = acc[r];
  const int m = lane >> 2, j = lane & 3;
  const int hu = q * 4 + j;
  const int bb = grp * GB + wv * 16 + m;
  float zi = zw[m * 17 + (0 + j)]  + bias4[0];
  float zf = zw[m * 17 + (4 + j)]  + bias4[1];
  float zg = zw[m * 17 + (8 + j)]  + bias4[2];
  float zo = zw[m * 17 + (12 + j)] + bias4[3];
  float cn = sigm(zf) * creg + sigm(zi) * tanhf(zg);
  creg = cn;
  float hn = sigm(zo) * tanhf(cn);
  ast(hout + (hu >> 3) * 1024 + bb * 8 + (hu & 7), packf(hn));
}

// Attention window for batch b — single-wave (wave 2; waves 0,1 are inside the
// LSTM3 gate concurrently — no __syncthreads allowed). Summation orders
// replicate the original chunked reductions bit-exactly.
template <bool F32>
__device__ void window_1w(const KArgs& a, int b, const unsigned* __restrict__ h1c,
                          unsigned* __restrict__ wout, int lane, float* ws) {
  float* slab = ws;         // 256
  float* winL = ws + 256;   // 30
  float* kapL = ws + 286;   // 10
  float* phiL = ws + 296;   // 64
  {
    const unsigned* p = h1c + (lane >> 1) * 1024 + b * 8 + (lane & 1) * 4;
    u64x2 d;
    ld16(d, p);
    waitvm<0>();
    f32x4 v;
    v[0] = unpackf((unsigned)d[0]);
    v[1] = unpackf((unsigned)(d[0] >> 32));
    v[2] = unpackf((unsigned)d[1]);
    v[3] = unpackf((unsigned)(d[1] >> 32));
    ((f32x4*)slab)[lane] = v;   // slab[lane*4 + j] = h1[lane*4 + j]
  }
  wfence();
  if (lane < 30) {
    float s = rin(a.in[12], lane, F32);
#pragma unroll
    for (int pp = 0; pp < 8; ++pp) {     // 8x32 chunking == original part[] order
      float p = 0.f;
      const float* hh = slab + pp * 32;
      if (F32) {
        const f32x4* w4 = (const f32x4*)((const float*)a.in[11] + (size_t)lane * HH + pp * 32);
#pragma unroll
        for (int j = 0; j < 8; ++j) {
          f32x4 v = w4[j];
          p += v[0] * hh[4 * j];     p += v[1] * hh[4 * j + 1];
          p += v[2] * hh[4 * j + 2]; p += v[3] * hh[4 * j + 3];
        }
      } else {
        const unsigned short* wr = (const unsigned short*)a.in[11] + (size_t)lane * HH + pp * 32;
#pragma unroll
        for (int j = 0; j < 4; ++j) {
          bf16s8 v = *(const bf16s8*)(wr + 8 * j);
#pragma unroll
          for (int e = 0; e < 8; ++e) p += bf2f((unsigned short)v[e]) * hh[8 * j + e];
        }
      }
      s += p;
    }
    float e = __expf(s);
    winL[lane] = e;
    if (lane >= 20) {
      int r = lane - 20;
      float kp = a.kappa[b * KK + r] + 0.1f * e;
      a.kappa[b * KK + r] = kp;
      kapL[r] = kp;
    }
  }
  wfence();
  {
    float u = (float)lane, s = 0.f;
#pragma unroll
    for (int r = 0; r < 10; ++r) {
      float d = kapL[r] - u;
      s += winL[r] * __expf(-winL[10 + r] * d * d);
    }
    phiL[lane] = s;
  }
  wfence();
  {
    float s = 0.f;
#pragma unroll 8
    for (int u = 0; u < 64; ++u)
      s += phiL[u] * rin(a.in[1], ((size_t)b * UU + u) * AA + lane, F32);
    ast(wout + (lane >> 3) * 1024 + b * 8 + (lane & 7), packf(s));
  }
}

// Output projections for timestep tt, batch b — split across waves 2 (half=0,
// outputs o=lane incl. softmax family) and 3 (half=1, outputs o=64+lane, lane<57).
// Reduction order == original (even/odd + half split). Waves independent: each
// has a private slab; zp/softmax entirely within wave 2.
template <bool F32>
__device__ void proj_w(const KArgs& a, int tt, const unsigned* __restrict__ h3b,
                       int b, int lane, int half, float* slab, float* zp) {
  {
    const unsigned* p = h3b + (lane >> 1) * 1024 + b * 8 + (lane & 1) * 4;
    u64x2 d;
    ld16(d, p);
    waitvm<0>();
    f32x4 v;
    v[0] = unpackf((unsigned)d[0]);
    v[1] = unpackf((unsigned)(d[0] >> 32));
    v[2] = unpackf((unsigned)d[1]);
    v[3] = unpackf((unsigned)(d[1] >> 32));
    ((f32x4*)slab)[lane] = v;
  }
  wfence();
  auto zo = [&](int o) -> float {
    const void* Wt; const void* bt; int rr;
    if (o == 0) { Wt = a.in[13]; bt = a.in[14]; rr = 0; }
    else {
      int fam = (o - 1) / 20; rr = (o - 1) % 20;
      Wt = a.in[15 + fam * 2]; bt = a.in[16 + fam * 2];
    }
    float z = 0.f;
#pragma unroll
    for (int hf = 0; hf < 2; ++hf) {       // even/odd + half split == original
      float s0 = hf ? 0.f : rin(bt, rr, F32), s1 = 0.f;
      const float* hh = slab + hf * 128;
      if (F32) {
        const f32x4* w4 = (const f32x4*)((const float*)Wt + (size_t)rr * HH + hf * 128);
#pragma unroll 8
        for (int j = 0; j < 32; ++j) {
          f32x4 v = w4[j];
          s0 += v[0] * hh[4 * j];     s1 += v[1] * hh[4 * j + 1];
          s0 += v[2] * hh[4 * j + 2]; s1 += v[3] * hh[4 * j + 3];
        }
      } else {
        const unsigned short* wr = (const unsigned short*)Wt + (size_t)rr * HH + hf * 128;
#pragma unroll 4
        for (int j = 0; j < 16; ++j) {
          bf16s8 v = *(const bf16s8*)(wr + 8 * j);
#pragma unroll
          for (int e = 0; e < 8; e += 2) {
            s0 += bf2f((unsigned short)v[e]) * hh[8 * j + e];
            s1 += bf2f((unsigned short)v[e + 1]) * hh[8 * j + e + 1];
          }
        }
      }
      z += s0 + s1;
    }
    return z;
  };
  size_t tb = (size_t)tt * BB + b;
  auto emit = [&](int o, float z) {
    if (o == 0) { a.out[tb] = 1.f / (1.f + __expf(z)); return; }   // sigmoid(-z)
    int fam = (o - 1) / 20, g = (o - 1) % 20;
    float val;
    if (fam == 0) {
      float mx = -1e30f;
      for (int jj = 0; jj < 20; ++jj) mx = fmaxf(mx, zp[1 + jj]);
      float den = 0.f;
      for (int jj = 0; jj < 20; ++jj) den += __expf(zp[1 + jj] - mx);
      val = __expf(z - mx) / den;
    } else if (fam <= 2) val = z;
    else if (fam <= 4) val = __expf(z);
    else val = tanhf(z);
    a.out[(size_t)102400 + (size_t)fam * 2048000 + tb * GG + g] = val;
  };
  if (half == 0) {
    float z1 = zo(lane);
    zp[lane] = z1;
    wfence();
    emit(lane, z1);
  } else {
    if (lane < 57) { float z2 = zo(64 + lane); emit(64 + lane, z2); }
  }
}

#define BAR_WORDS (256 + 8192 + 4096)

__global__ void __launch_bounds__(256) bar_init_kernel(unsigned* bar) {
  for (int i = threadIdx.x; i < BAR_WORDS; i += 256) bar[i] = 0u;
}

__global__ void __launch_bounds__(256, 1) hsm_kernel(KArgs a) {
  __shared__ unsigned short B1h[5632], B1l[5632];
  __shared__ unsigned short B2h[9728], B2l[9728];
  __shared__ unsigned short B3h[9728], B3l[9728];
  __shared__ float zls[4 * 16 * 17];
  __shared__ __align__(16) float misc[576];

  const int tid = threadIdx.x;
  const int wg = blockIdx.x;
  const int grp = wg >> 6;   // batch group of 32
  const int q = wg & 63;     // hidden quad
  const int wave = tid >> 6, lane = tid & 63;
  unsigned* cnt_full = a.bar;
  const unsigned* dz = a.bar + 160;   // zeroed 32B line, never written after init
  unsigned* bfl = a.bar + 256 + grp * 64 * 32;          // 64 flags, 128B apart
  unsigned* afl = a.bar + 256 + 8192 + grp * 32 * 32;   // 32 flags, 128B apart
  unsigned* myb = bfl + q * 32;
  unsigned* mya = afl + q * 32;   // valid only for q<GB

  // all-to-all flag barrier: lane0 stores own flag, wave0 lanes poll all 64.
  // No shared-line RMW in steady state.
  auto barB = [&](unsigned tgt) {
    __syncthreads();                 // drains each wave's vmcnt before s_barrier
    if (wave == 0) {
      if (lane == 0) ast(myb, tgt);
      const unsigned* fp = bfl + lane * 32;
      unsigned v = ald(fp);
      while (v < tgt) { __builtin_amdgcn_s_sleep(1); v = ald(fp); }
    }
    __syncthreads();
  };
  // asymmetric A-barrier: only the 32 window WGs signal (straight after their
  // w stores drain); everyone polls those 32 flags.
  auto waitA = [&](unsigned tgt) {
    __syncthreads();
    if (wave == 0) {
      const unsigned* fp = afl + (lane & 31) * 32;
      unsigned v = ald(fp);
      while (v < tgt) { __builtin_amdgcn_s_sleep(1); v = ald(fp); }
    }
    __syncthreads();
  };

  // ---- dtype sniff (uniform) ----
  bool isf32;
  {
    const unsigned short* w = (const unsigned short*)a.in[3];
    int cnt = 0;
    for (int i = 0; i < 128; ++i) {
      float v = bf2f(w[i]);
      if (!(fabsf(v) <= 100.f)) cnt++;
    }
    isf32 = (cnt > 0);
  }

  // ---- init (all cross-WG state through sc1 atomics) ----
  const int g0 = wg * 256 + tid, gs = 65536;
  if (isf32) {
    const float* xp = (const float*)a.in[0];
    for (int i = g0; i < 307200; i += gs) ast(a.xu + i, packf(xp[i]));
  } else {
    const unsigned short* xp = (const unsigned short*)a.in[0];
    for (int i = g0; i < 307200; i += gs) ast(a.xu + i, (unsigned)xp[i]);
  }
  if (g0 < 32768) {
    ast(a.h1[0] + g0, 0u); ast(a.h1[1] + g0, 0u);
    ast(a.h2[0] + g0, 0u); ast(a.h2[1] + g0, 0u);
    ast(a.h3[0] + g0, 0u); ast(a.h3[1] + g0, 0u);
  }
  if (g0 < 16384) ast(a.wu + g0, 0x00003F80u);   // both w planes = 1.0
  if (q < GB && tid < KK) a.kappa[(grp * GB + q) * KK + tid] = 0.f;

  float bs1[4], bs2[4], bs3[4];
  {
    const int hu = q * 4 + (tid & 3);
#pragma unroll
    for (int g = 0; g < 4; ++g) {
      bs1[g] = rin(a.in[4], g * HH + hu, isf32);
      bs2[g] = rin(a.in[7], g * HH + hu, isf32);
      bs3[g] = rin(a.in[10], g * HH + hu, isf32);
    }
  }
  float c1r = 0.f, c2r = 0.f, c3r = 0.f;

  fillB(B1h, B1l, a.in[2], a.in[3], 352, 67, 72, 72, q, tid, isf32);
  fillB(B2h, B2l, a.in[5], a.in[6], 608, 323, 328, 328, q, tid, isf32);
  fillB(B3h, B3l, a.in[8], a.in[9], 608, 323, 328, 328, q, tid, isf32);

  // full-grid barrier once (counter poll; one-time cost)
  __syncthreads();
  if (tid == 0) {
    unsigned old = __hip_atomic_fetch_add(cnt_full, 1u, __ATOMIC_RELAXED,
                                          __HIP_MEMORY_SCOPE_AGENT);
    if (old + 1u != NWG)
      while (ald(cnt_full) < NWG) __builtin_amdgcn_s_sleep(1);
  }
  __syncthreads();

  // Convention: state(t) lives in plane[t&1]; t=-1 -> plane 1 (zeros / ones).
  // prologue: LSTM1(0) on waves 2,3: rec h1(-1)=0, w(-1)=ones -> h1[0]
  gate_mfma<11, false, 2>(a.xu, a.wu + 8192, a.h1[1], nullptr, dz, B1h, B1l,
                          bs1, c1r, a.h1[0], grp, q, zls, tid);
  barB(1);

  // 2-phase pipeline:
  //  A(t): waves01 LSTM3(t-1) | wave2 q<32 window(t)+aflag | waves23 q>=32 proj(t-2)
  //  B(t): waves01 LSTM2(t)   | waves23 LSTM1(t+1)
  for (int t = 0; t < TT; ++t) {
    const int p = t & 1, pm = 1 - p;
    // ---- phase A ----
    if (t >= 1)
      gate_mfma<19, true, 0>(a.xu + (size_t)(t - 1) * BB * 3, a.wu + pm * 8192,
                             a.h2[pm], a.h3[p], dz, B3h, B3l, bs3, c3r, a.h3[pm],
                             grp, q, zls, tid);
    if (q < GB) {
      if (wave == 2) {
        if (isf32) window_1w<true>(a, grp * GB + q, a.h1[p], a.wu + p * 8192, lane, misc);
        else       window_1w<false>(a, grp * GB + q, a.h1[p], a.wu + p * 8192, lane, misc);
        vdrain();                     // w stores complete before the flag
        ast(mya, (unsigned)(t + 1));
      }
    } else if (t >= 2 && (wave == 2 || wave == 3)) {
      const int half = wave - 2;
      float* slab = misc + half * 256;
      if (isf32) proj_w<true>(a, t - 2, a.h3[p], grp * GB + q - GB, lane, half, slab, misc + 512);
      else       proj_w<false>(a, t - 2, a.h3[p], grp * GB + q - GB, lane, half, slab, misc + 512);
    }
    waitA((unsigned)(t + 1));
    // ---- phase B ----
    gate_mfma<19, true, 0>(a.xu + (size_t)t * BB * 3, a.wu + p * 8192,
                           a.h1[p], a.h2[pm], dz, B2h, B2l, bs2, c2r, a.h2[p],
                           grp, q, zls, tid);
    if (t < TT - 1)
      gate_mfma<11, false, 2>(a.xu + (size_t)(t + 1) * BB * 3, a.wu + p * 8192,
                              a.h1[p], nullptr, dz, B1h, B1l, bs1, c1r, a.h1[pm],
                              grp, q, zls, tid);
    barB((unsigned)(t + 2));
  }

  // epilogue phase A(TT): LSTM3(TT-1) + proj(TT-2)   [p=0, pm=1 for t=TT]
  gate_mfma<19, true, 0>(a.xu + (size_t)(TT - 1) * BB * 3, a.wu + 8192,
                         a.h2[1], a.h3[0], dz, B3h, B3l, bs3, c3r, a.h3[1],
                         grp, q, zls, tid);
  if (q >= GB && (wave == 2 || wave == 3)) {
    const int half = wave - 2;
    float* slab = misc + half * 256;
    if (isf32) proj_w<true>(a, TT - 2, a.h3[0], grp * GB + q - GB, lane, half, slab, misc + 512);
    else       proj_w<false>(a, TT - 2, a.h3[0], grp * GB + q - GB, lane, half, slab, misc + 512);
  }
  barB((unsigned)(TT + 2));
  // final proj(TT-1): h3(TT-1) lives in plane 1 (TT-1 odd)
  if (q >= GB && (wave == 2 || wave == 3)) {
    const int half = wave - 2;
    float* slab = misc + half * 256;
    if (isf32) proj_w<true>(a, TT - 1, a.h3[1], grp * GB + q - GB, lane, half, slab, misc + 512);
    else       proj_w<false>(a, TT - 1, a.h3[1], grp * GB + q - GB, lane, half, slab, misc + 512);
  }
}

extern "C" void kernel_launch(void* const* d_in, const int* in_sizes, int n_in,
                              void* d_out, int out_size, void* d_ws, size_t ws_size,
                              hipStream_t stream) {
  KArgs a;
  for (int i = 0; i < 27; ++i) a.in[i] = d_in[i];
  a.out = (float*)d_out;

  char* ws = (char*)d_ws;
  size_t off = 0;
  auto take = [&](size_t bytes) {
    void* p = ws + off;
    off = (off + bytes + 127) & ~(size_t)127;
    return p;
  };
  a.kappa = (float*)take(1280 * 4);
  a.wu    = (unsigned*)take(16384 * 4);     // 2 planes
  a.h1[0] = (unsigned*)take(32768 * 4);
  a.h1[1] = (unsigned*)take(32768 * 4);
  a.h2[0] = (unsigned*)take(32768 * 4);
  a.h2[1] = (unsigned*)take(32768 * 4);
  a.h3[0] = (unsigned*)take(32768 * 4);
  a.h3[1] = (unsigned*)take(32768 * 4);
  a.xu    = (unsigned*)take(307200 * 4);
  a.bar   = (unsigned*)take(BAR_WORDS * 4);

  bar_init_kernel<<<1, 256, 0, stream>>>(a.bar);
  hsm_kernel<<<NWG, 256, 0, stream>>>(a);
}

// Round 10
// 12498.697 us; speedup vs baseline: 1.1190x; 1.1190x over previous
//
#include <hip/hip_runtime.h>
#include <utility>

#define TT 800
#define BB 128
#define HH 256
#define UU 64
#define AA 64
#define KK 10
#define GG 20
#define NWG 256
#define GB 32          // batches per group
#define NGRP 4

typedef float f32x4 __attribute__((ext_vector_type(4)));
typedef __bf16 bf16y8 __attribute__((ext_vector_type(8)));
typedef short bf16s8 __attribute__((ext_vector_type(8)));
typedef unsigned long long u64x2 __attribute__((ext_vector_type(2)));

__device__ __forceinline__ float bf2f(unsigned short u) {
  return __uint_as_float(((unsigned int)u) << 16);
}
__device__ __forceinline__ unsigned short f2bf(float f) {
  unsigned int x = __float_as_uint(f);
  x += 0x7FFFu + ((x >> 16) & 1u);
  return (unsigned short)(x >> 16);
}
__device__ __forceinline__ unsigned packf(float v) {
  unsigned short hi = f2bf(v);
  unsigned short lo = f2bf(v - bf2f(hi));
  return (unsigned)hi | ((unsigned)lo << 16);
}
__device__ __forceinline__ float unpackf(unsigned u) {
  return bf2f((unsigned short)(u & 0xFFFF)) + bf2f((unsigned short)(u >> 16));
}
__device__ __forceinline__ float sigm(float x) { return 1.0f / (1.0f + __expf(-x)); }
__device__ __forceinline__ float rin(const void* p, size_t i, bool f32) {
  return f32 ? ((const float*)p)[i] : bf2f(((const unsigned short*)p)[i]);
}
__device__ __forceinline__ bf16y8 ld8(const unsigned short* p) {
  return __builtin_bit_cast(bf16y8, *(const bf16s8*)p);
}

// agent-scope relaxed atomics for flag stores / state stores
__device__ __forceinline__ unsigned ald(const unsigned* p) {
  return __hip_atomic_load(p, __ATOMIC_RELAXED, __HIP_MEMORY_SCOPE_AGENT);
}
__device__ __forceinline__ void ast(unsigned* p, unsigned v) {
  __hip_atomic_store(p, v, __ATOMIC_RELAXED, __HIP_MEMORY_SCOPE_AGENT);
}

// Coherent 16B read (normal read path, full pipelining, bypasses stale caches).
// NOTE: no completion wait inside — pair with waitvm<N>() before consuming.
__device__ __forceinline__ void ld16(u64x2& d, const unsigned* p) {
  asm volatile("global_load_dwordx4 %0, %1, off sc0 sc1" : "=v"(d) : "v"(p));
}
// Counted vmem wait + scheduler fence (rule #18: keep consumers below the wait).
template <int N>
__device__ __forceinline__ void waitvm() {
  asm volatile("s_waitcnt vmcnt(%0)" :: "i"(N) : "memory");
  __builtin_amdgcn_sched_barrier(0);
}

template <typename F, int... I>
__device__ __forceinline__ void unroll_seq(F&& f, std::integer_sequence<int, I...>) {
  (f(std::integral_constant<int, I>{}), ...);
}

// State planes are k-major: plane[kblk][b][j], kblk=hu>>3, j=hu&7.
// Flat: kblk*1024 + b*8 + j  (1024 = BB*8). 32B per (kblk,b): one dwordx4 pair.

struct KArgs {
  const void* in[27];
  float* out;
  float* kappa;
  unsigned *xu;               // packed x, [t][b][3], 307200
  unsigned *wu;               // packed w, k-major, 8192
  unsigned *h1[2], *h2[2], *h3[2];  // packed h planes, k-major, 32768 each
  unsigned* bar;              // [0] full cnt; [32..] grp cnts; [160..167] zero line;
                              // [256..8447] b-flags; [8448..] w-ready aflags
};

// LDS B-fragment fill, hi/lo planes
__device__ void fillB(unsigned short* Bhi, unsigned short* Blo, const void* Wih,
                      const void* Whh, int KP, int ihCols, int ihEnd, int hhStart,
                      int q, int tid, bool f32) {
  int total = KP * 16;
  for (int idx = tid; idx < total; idx += 256) {
    int k = idx >> 4, n = idx & 15;
    int row = (n >> 2) * HH + q * 4 + (n & 3);
    float v = 0.f;
    if (k < 3) v = rin(Wih, (size_t)row * ihCols + k, f32);
    else if (k >= 8 && k < ihEnd) v = rin(Wih, (size_t)row * ihCols + (k - 5), f32);
    else if (k >= hhStart && k < hhStart + 256) v = rin(Whh, (size_t)row * HH + (k - hhStart), f32);
    unsigned short hi = f2bf(v);
    int a = ((k >> 3) * 16 + n) * 8 + (k & 7);
    Bhi[a] = hi;
    Blo[a] = f2bf(v - bf2f(hi));
  }
}

// ---------------- standard gate (round-7 verbatim) ----------------
template <int KC, bool R3, int WB>
__device__ __forceinline__ void gate_mfma(
    const unsigned* __restrict__ xt, const unsigned* __restrict__ wu,
    const unsigned* __restrict__ r2, const unsigned* __restrict__ r3,
    const unsigned* __restrict__ dz,
    const unsigned short* __restrict__ Bhi, const unsigned short* __restrict__ Blo,
    const float* __restrict__ bias4, float& creg, unsigned* __restrict__ hout,
    int grp, int q, float* zls, int tid) {
  const int wave = tid >> 6, lane = tid & 63;
  if ((wave >> 1) != (WB >> 1)) return;
  const int wv = wave & 1;
  const int n15 = lane & 15, quad = lane >> 4;
  const int b = grp * GB + wv * 16 + n15;

  unsigned xv0 = 0, xv1 = 0, xv2 = 0;
  if (quad == 0) {
    xv0 = xt[b * 3 + 0];
    xv1 = xt[b * 3 + 1];
    xv2 = xt[b * 3 + 2];
  }
  asm volatile("" :: "v"(xv0), "v"(xv1), "v"(xv2));

  constexpr int DEP = 12;
  u64x2 buf[DEP][2];

  auto addr = [&](int kc) -> const unsigned* {
    const int k0 = kc * 32 + quad * 8;
    if (kc == 0 && quad == 0) return dz;
    if (k0 < 72) return wu + ((k0 - 8) >> 3) * 1024 + b * 8;
    if (k0 < 328) return r2 + ((k0 - 72) >> 3) * 1024 + b * 8;
    if (R3 && k0 < 584) return r3 + ((k0 - 328) >> 3) * 1024 + b * 8;
    return dz;
  };
  auto issue = [&](int kc, int slot) {
    const unsigned* p = addr(kc);
    ld16(buf[slot][0], p);
    ld16(buf[slot][1], p + 4);
  };

#pragma unroll
  for (int kc = 0; kc < DEP && kc < KC; ++kc) issue(kc, kc);

  f32x4 acc = {0.f, 0.f, 0.f, 0.f};

  unroll_seq([&](auto kcc) {
    constexpr int kc = decltype(kcc)::value;
    constexpr int end = (kc + DEP < KC) ? (kc + DEP) : KC;
    waitvm<2 * (end - kc - 1)>();
    u64x2* sp = buf[kc % DEP];
    unsigned long long s[4] = { sp[0][0], sp[0][1], sp[1][0], sp[1][1] };
    bf16s8 th, tl;
#pragma unroll
    for (int j = 0; j < 4; ++j) {
      unsigned lo32 = (unsigned)s[j], hi32 = (unsigned)(s[j] >> 32);
      th[2 * j] = (short)(lo32 & 0xFFFFu);     tl[2 * j] = (short)(lo32 >> 16);
      th[2 * j + 1] = (short)(hi32 & 0xFFFFu); tl[2 * j + 1] = (short)(hi32 >> 16);
    }
    if constexpr (kc == 0) {
      if (quad == 0) {
        th[0] = (short)(xv0 & 0xFFFFu); tl[0] = (short)(xv0 >> 16);
        th[1] = (short)(xv1 & 0xFFFFu); tl[1] = (short)(xv1 >> 16);
        th[2] = (short)(xv2 & 0xFFFFu); tl[2] = (short)(xv2 >> 16);
      }
    }
    bf16y8 ah = __builtin_bit_cast(bf16y8, th);
    bf16y8 al = __builtin_bit_cast(bf16y8, tl);
    const int boff = ((kc * 4 + quad) * 16 + n15) * 8;
    bf16y8 bh = ld8(Bhi + boff), bl = ld8(Blo + boff);
    acc = __builtin_amdgcn_mfma_f32_16x16x32_bf16(ah, bh, acc, 0, 0, 0);
    acc = __builtin_amdgcn_mfma_f32_16x16x32_bf16(ah, bl, acc, 0, 0, 0);
    acc = __builtin_amdgcn_mfma_f32_16x16x32_bf16(al, bh, acc, 0, 0, 0);
    if constexpr (kc + DEP < KC) issue(kc + DEP, kc % DEP);
  }, std::make_integer_sequence<int, KC>{});

  float* zw = zls + wave * (16 * 17);
#pragma unroll
  for (int r = 0; r < 4; ++r) zw[(quad * 4 + r) * 17 + n15] = acc[r];
  const int m = lane >> 2, j = lane & 3;
  const int hu = q * 4 + j;
  const int bb = grp * GB + wv * 16 + m;
  float zi = zw[m * 17 + (0 + j)]  + bias4[0];
  float zf = zw[m * 17 + (4 + j)]  + bias4[1];
  float zg = zw[m * 17 + (8 + j)]  + bias4[2];
  float zo = zw[m * 17 + (12 + j)] + bias4[3];
  float cn = sigm(zf) * creg + sigm(zi) * tanhf(zg);
  creg = cn;
  float hn = sigm(zo) * tanhf(cn);
  ast(hout + (hu >> 3) * 1024 + bb * 8 + (hu & 7), packf(hn));
}

// ---------------- late-w gate: LSTM2 (KC=19, waves 0,1) ----------------
// Issue order: kc3..14 (h1/h2 prefetch) -> poll 32 w-ready flags -> kc0..2 (w)
// into side buffers. MFMA order stays kc0..18 (bit-exact). vmcnt retires in
// issue order on gfx9, so waits: kc0:4, kc1:2, kc2:0, kc3-14:none,
// kc15:6, kc16:4, kc17:2, kc18:0. Ring refills (kc15..18) at kc3..6.
template <int kc> constexpr int lw_wait() {
  return kc == 0 ? 4 : kc == 1 ? 2 : kc == 2 ? 0 :
         kc == 15 ? 6 : kc == 16 ? 4 : kc == 17 ? 2 : kc == 18 ? 0 : -1;
}
__device__ __forceinline__ void gate_mfma_lw(
    const unsigned* __restrict__ xt, const unsigned* __restrict__ wu,
    const unsigned* __restrict__ r2, const unsigned* __restrict__ r3,
    const unsigned* __restrict__ dz,
    const unsigned short* __restrict__ Bhi, const unsigned short* __restrict__ Blo,
    const float* __restrict__ bias4, float& creg, unsigned* __restrict__ hout,
    const unsigned* __restrict__ afl, unsigned tgt,
    int grp, int q, float* zls, int tid) {
  constexpr int KC = 19, DEP = 12;
  const int wave = tid >> 6, lane = tid & 63;
  if (wave >= 2) return;
  const int wv = wave & 1;
  const int n15 = lane & 15, quad = lane >> 4;
  const int b = grp * GB + wv * 16 + n15;

  unsigned xv0 = 0, xv1 = 0, xv2 = 0;
  if (quad == 0) {
    xv0 = xt[b * 3 + 0];
    xv1 = xt[b * 3 + 1];
    xv2 = xt[b * 3 + 2];
  }
  asm volatile("" :: "v"(xv0), "v"(xv1), "v"(xv2));

  u64x2 buf[DEP][2];
  u64x2 wbuf[3][2];

  auto addr = [&](int kc) -> const unsigned* {
    const int k0 = kc * 32 + quad * 8;
    if (kc == 0 && quad == 0) return dz;
    if (k0 < 72) return wu + ((k0 - 8) >> 3) * 1024 + b * 8;
    if (k0 < 328) return r2 + ((k0 - 72) >> 3) * 1024 + b * 8;
    if (k0 < 584) return r3 + ((k0 - 328) >> 3) * 1024 + b * 8;
    return dz;
  };
  auto issue = [&](int kc, int slot) {
    const unsigned* p = addr(kc);
    ld16(buf[slot][0], p);
    ld16(buf[slot][1], p + 4);
  };

  // prefetch all w-independent kcs first (h1/h2 region)
#pragma unroll
  for (int kc = 3; kc < 15; ++kc) issue(kc, kc % DEP);

  // wait for the 32 window producers (w(t) at the coherence point)
  {
    const unsigned* fp = afl + (lane & 31) * 32;
    unsigned v = ald(fp);
    while (v < tgt) { __builtin_amdgcn_s_sleep(1); v = ald(fp); }
  }

  // now the w-region loads
#pragma unroll
  for (int kc = 0; kc < 3; ++kc) {
    const unsigned* p = addr(kc);
    ld16(wbuf[kc][0], p);
    ld16(wbuf[kc][1], p + 4);
  }

  f32x4 acc = {0.f, 0.f, 0.f, 0.f};

  unroll_seq([&](auto kcc) {
    constexpr int kc = decltype(kcc)::value;
    constexpr int wn = lw_wait<kc>();
    if constexpr (wn >= 0) waitvm<wn>();
    u64x2* sp = (kc < 3) ? wbuf[kc] : buf[kc % DEP];
    unsigned long long s[4] = { sp[0][0], sp[0][1], sp[1][0], sp[1][1] };
    bf16s8 th, tl;
#pragma unroll
    for (int j = 0; j < 4; ++j) {
      unsigned lo32 = (unsigned)s[j], hi32 = (unsigned)(s[j] >> 32);
      th[2 * j] = (short)(lo32 & 0xFFFFu);     tl[2 * j] = (short)(lo32 >> 16);
      th[2 * j + 1] = (short)(hi32 & 0xFFFFu); tl[2 * j + 1] = (short)(hi32 >> 16);
    }
    if constexpr (kc == 0) {
      if (quad == 0) {
        th[0] = (short)(xv0 & 0xFFFFu); tl[0] = (short)(xv0 >> 16);
        th[1] = (short)(xv1 & 0xFFFFu); tl[1] = (short)(xv1 >> 16);
        th[2] = (short)(xv2 & 0xFFFFu); tl[2] = (short)(xv2 >> 16);
      }
    }
    bf16y8 ah = __builtin_bit_cast(bf16y8, th);
    bf16y8 al = __builtin_bit_cast(bf16y8, tl);
    const int boff = ((kc * 4 + quad) * 16 + n15) * 8;
    bf16y8 bh = ld8(Bhi + boff), bl = ld8(Blo + boff);
    acc = __builtin_amdgcn_mfma_f32_16x16x32_bf16(ah, bh, acc, 0, 0, 0);
    acc = __builtin_amdgcn_mfma_f32_16x16x32_bf16(ah, bl, acc, 0, 0, 0);
    acc = __builtin_amdgcn_mfma_f32_16x16x32_bf16(al, bh, acc, 0, 0, 0);
    if constexpr (kc >= 3 && kc + DEP < KC) issue(kc + DEP, kc % DEP);
  }, std::make_integer_sequence<int, KC>{});

  float* zw = zls + wave * (16 * 17);
#pragma unroll
  for (int r = 0; r < 4; ++r) zw[(quad * 4 + r) * 17 + n15] = acc[r];
  const int m = lane >> 2, j = lane & 3;
  const int hu = q * 4 + j;
  const int bb = grp * GB + wv * 16 + m;
  float zi = zw[m * 17 + (0 + j)]  + bias4[0];
  float zf = zw[m * 17 + (4 + j)]  + bias4[1];
  float zg = zw[m * 17 + (8 + j)]  + bias4[2];
  float zo = zw[m * 17 + (12 + j)] + bias4[3];
  float cn = sigm(zf) * creg + sigm(zi) * tanhf(zg);
  creg = cn;
  float hn = sigm(zo) * tanhf(cn);
  ast(hout + (hu >> 3) * 1024 + bb * 8 + (hu & 7), packf(hn));
}

// Attention window for batch b (whole WG). Slab laid out stride-33.
// Summation orders replicate round-0 bit-exactly. (round-7 verbatim)
template <bool F32>
__device__ void window_stage(const KArgs& a, int b, const unsigned* __restrict__ h1c,
                             int tid, float* misc) {
  float* slab = misc;        // 264 (8*33)
  float* part = misc + 264;  // 240
  float* win  = misc + 508;  // 30
  float* kap  = misc + 538;  // 10
  float* phi  = misc + 552;  // 64
  const int wave = tid >> 6, lane = tid & 63;
  if (wave == 0) {
    const unsigned* p = h1c + (lane >> 1) * 1024 + b * 8 + (lane & 1) * 4;
    u64x2 d;
    ld16(d, p);
    waitvm<0>();
    const int hu0 = (lane >> 1) * 8 + (lane & 1) * 4;
    float* s4 = slab + (hu0 >> 5) * 33 + (hu0 & 31);
    s4[0] = unpackf((unsigned)d[0]);
    s4[1] = unpackf((unsigned)(d[0] >> 32));
    s4[2] = unpackf((unsigned)d[1]);
    s4[3] = unpackf((unsigned)(d[1] >> 32));
  }
  __syncthreads();
  if (tid < 240) {
    int r = tid >> 3, pp = tid & 7;
    const float* hh = slab + pp * 33;
    float s = 0.f;
    if (F32) {
      const f32x4* w4 = (const f32x4*)((const float*)a.in[11] + (size_t)r * HH + pp * 32);
#pragma unroll
      for (int j = 0; j < 8; ++j) {
        f32x4 v = w4[j];
        s += v[0] * hh[4 * j];     s += v[1] * hh[4 * j + 1];
        s += v[2] * hh[4 * j + 2]; s += v[3] * hh[4 * j + 3];
      }
    } else {
      const unsigned short* wr = (const unsigned short*)a.in[11] + (size_t)r * HH + pp * 32;
#pragma unroll
      for (int j = 0; j < 4; ++j) {
        bf16s8 v = *(const bf16s8*)(wr + 8 * j);
#pragma unroll
        for (int e = 0; e < 8; ++e) s += bf2f((unsigned short)v[e]) * hh[8 * j + e];
      }
    }
    part[tid] = s;
  }
  __syncthreads();
  if (tid < 30) {
    float s = rin(a.in[12], tid, F32);
#pragma unroll
    for (int i = 0; i < 8; ++i) s += part[tid * 8 + i];
    win[tid] = __expf(s);
  }
  __syncthreads();
  if (tid < 10) {
    float kp = a.kappa[b * KK + tid] + 0.1f * win[20 + tid];
    a.kappa[b * KK + tid] = kp;
    kap[tid] = kp;
  }
  __syncthreads();
  if (tid < 64) {
    float u = (float)tid, s = 0.f;
#pragma unroll
    for (int r = 0; r < 10; ++r) {
      float d = kap[r] - u;
      s += win[r] * __expf(-win[10 + r] * d * d);
    }
    phi[tid] = s;
  }
  __syncthreads();
  if (tid < 64) {
    float s = 0.f;
    for (int u = 0; u < 64; ++u) s += phi[u] * rin(a.in[1], ((size_t)b * UU + u) * AA + tid, F32);
    ast(a.wu + (tid >> 3) * 1024 + b * 8 + (tid & 7), packf(s));
  }
}

// Output projections for timestep tt, batch b (whole WG). (round-7 verbatim)
template <bool F32>
__device__ void proj_stage(const KArgs& a, int tt, const unsigned* __restrict__ h3b,
                           int b, int tid, float* misc) {
  float* shm  = misc;        // 256
  float* part = misc + 256;  // 242
  float* zp   = misc + 500;  // 121
  const int wave = tid >> 6, lane = tid & 63;
  if (wave == 0) {
    const unsigned* p = h3b + (lane >> 1) * 1024 + b * 8 + (lane & 1) * 4;
    u64x2 d;
    ld16(d, p);
    waitvm<0>();
    const int hu0 = (lane >> 1) * 8 + (lane & 1) * 4;
    shm[hu0 + 0] = unpackf((unsigned)d[0]);
    shm[hu0 + 1] = unpackf((unsigned)(d[0] >> 32));
    shm[hu0 + 2] = unpackf((unsigned)d[1]);
    shm[hu0 + 3] = unpackf((unsigned)(d[1] >> 32));
  }
  __syncthreads();
  if (tid < 242) {
    int o = tid >> 1, hf = tid & 1;
    const void* Wt;
    const void* bt;
    int rr;
    if (o == 0) {
      Wt = a.in[13]; bt = a.in[14]; rr = 0;
    } else {
      int fam = (o - 1) / 20;
      rr = (o - 1) % 20;
      Wt = a.in[15 + fam * 2];
      bt = a.in[16 + fam * 2];
    }
    float s0 = hf ? 0.f : rin(bt, rr, F32), s1 = 0.f;
    const float* hh = shm + hf * 128;
    if (F32) {
      const f32x4* w4 = (const f32x4*)((const float*)Wt + (size_t)rr * HH + hf * 128);
#pragma unroll 8
      for (int j = 0; j < 32; ++j) {
        f32x4 v = w4[j];
        s0 += v[0] * hh[4 * j];     s1 += v[1] * hh[4 * j + 1];
        s0 += v[2] * hh[4 * j + 2]; s1 += v[3] * hh[4 * j + 3];
      }
    } else {
      const unsigned short* wr = (const unsigned short*)Wt + (size_t)rr * HH + hf * 128;
#pragma unroll 4
      for (int j = 0; j < 16; ++j) {
        bf16s8 v = *(const bf16s8*)(wr + 8 * j);
#pragma unroll
        for (int e = 0; e < 8; e += 2) {
          s0 += bf2f((unsigned short)v[e]) * hh[8 * j + e];
          s1 += bf2f((unsigned short)v[e + 1]) * hh[8 * j + e + 1];
        }
      }
    }
    part[tid] = s0 + s1;
  }
  __syncthreads();
  if (tid < 121) zp[tid] = part[tid * 2] + part[tid * 2 + 1];
  __syncthreads();
  size_t tb = (size_t)tt * BB + b;
  if (tid == 0) {
    a.out[tb] = 1.f / (1.f + __expf(zp[0]));  // sigmoid(-z)
  } else if (tid < 121) {
    int fam = (tid - 1) / 20, g = (tid - 1) % 20;
    float z = zp[tid];
    float val;
    if (fam == 0) {
      float mx = -1e30f;
      for (int jj = 0; jj < 20; ++jj) mx = fmaxf(mx, zp[1 + jj]);
      float den = 0.f;
      for (int jj = 0; jj < 20; ++jj) den += __expf(zp[1 + jj] - mx);
      val = __expf(z - mx) / den;
    } else if (fam <= 2) {
      val = z;
    } else if (fam <= 4) {
      val = __expf(z);
    } else {
      val = tanhf(z);
    }
    a.out[(size_t)102400 + (size_t)fam * 2048000 + tb * GG + g] = val;
  }
}

#define BAR_WORDS (256 + NWG * 32 + 4096)

__global__ void __launch_bounds__(256) bar_init_kernel(unsigned* bar) {
  for (int i = threadIdx.x; i < BAR_WORDS; i += 256) bar[i] = 0u;
}

__global__ void __launch_bounds__(256, 1) hsm_kernel(KArgs a) {
  __shared__ unsigned short B1h[5632], B1l[5632];
  __shared__ unsigned short B2h[9728], B2l[9728];
  __shared__ unsigned short B3h[9728], B3l[9728];
  __shared__ float zls[4 * 16 * 17];
  __shared__ float misc[768];
  __shared__ unsigned islast;

  const int tid = threadIdx.x;
  const int wg = blockIdx.x;
  const int grp = wg >> 6;   // batch group of 32
  const int q = wg & 63;     // hidden quad
  unsigned* cnt_full = a.bar;
  unsigned* cnt_grp  = a.bar + 32 * (1 + grp);
  unsigned* flags    = a.bar + 256;
  unsigned* myflag   = flags + wg * 32;
  const unsigned* dz = a.bar + 160;   // zeroed 32B line, never written after init
  unsigned* afl = a.bar + 256 + NWG * 32 + grp * 32 * 32;  // 32 w-ready flags, 128B apart
  unsigned* mya = afl + q * 32;   // valid only for q<GB

  auto barrier = [&](unsigned* cnt, unsigned target, unsigned fv, int nfl, int flbase) {
    __syncthreads();
    if (tid == 0) {
      unsigned old = __hip_atomic_fetch_add(cnt, 1u, __ATOMIC_RELAXED,
                                            __HIP_MEMORY_SCOPE_AGENT);
      islast = (old == target - 1u) ? 1u : 0u;
    }
    __syncthreads();
    if (islast) {
      if (tid < nfl) ast(flags + (flbase + tid) * 32, fv);
    } else if (tid == 0) {
      while (ald(myflag) < fv) __builtin_amdgcn_s_sleep(2);
    }
    __syncthreads();
  };

  // ---- dtype sniff (uniform) ----
  bool isf32;
  {
    const unsigned short* w = (const unsigned short*)a.in[3];
    int cnt = 0;
    for (int i = 0; i < 128; ++i) {
      float v = bf2f(w[i]);
      if (!(fabsf(v) <= 100.f)) cnt++;
    }
    isf32 = (cnt > 0);
  }

  // ---- init (all cross-WG state through sc1 atomics) ----
  const int g0 = wg * 256 + tid, gs = 65536;
  if (isf32) {
    const float* xp = (const float*)a.in[0];
    for (int i = g0; i < 307200; i += gs) ast(a.xu + i, packf(xp[i]));
  } else {
    const unsigned short* xp = (const unsigned short*)a.in[0];
    for (int i = g0; i < 307200; i += gs) ast(a.xu + i, (unsigned)xp[i]);
  }
  if (g0 < 32768) {
    ast(a.h1[0] + g0, 0u); ast(a.h1[1] + g0, 0u);
    ast(a.h2[0] + g0, 0u); ast(a.h2[1] + g0, 0u);
    ast(a.h3[0] + g0, 0u); ast(a.h3[1] + g0, 0u);
  }
  if (g0 < 8192) ast(a.wu + g0, 0x00003F80u);   // w init = 1.0 (uniform in any layout)
  if (q < GB && tid < KK) a.kappa[(grp * GB + q) * KK + tid] = 0.f;

  float bs1[4], bs2[4], bs3[4];
  {
    const int hu = q * 4 + (tid & 3);
#pragma unroll
    for (int g = 0; g < 4; ++g) {
      bs1[g] = rin(a.in[4], g * HH + hu, isf32);
      bs2[g] = rin(a.in[7], g * HH + hu, isf32);
      bs3[g] = rin(a.in[10], g * HH + hu, isf32);
    }
  }
  float c1r = 0.f, c2r = 0.f, c3r = 0.f;

  fillB(B1h, B1l, a.in[2], a.in[3], 352, 67, 72, 72, q, tid, isf32);
  fillB(B2h, B2l, a.in[5], a.in[6], 608, 323, 328, 328, q, tid, isf32);
  fillB(B3h, B3l, a.in[8], a.in[9], 608, 323, 328, 328, q, tid, isf32);
  barrier(cnt_full, NWG, 1, NWG, 0);   // full grid once

  unsigned ph = 0;

  // prologue: LSTM1(t=0): rec h1[0]=0, w=ones -> h1[1] (waves 2,3)
  gate_mfma<11, false, 2>(a.xu, a.wu, a.h1[0], nullptr, dz, B1h, B1l, bs1, c1r,
                          a.h1[1], grp, q, zls, tid);
  ++ph; barrier(cnt_grp, ph * 64u, ph + 1u, 64, grp * 64);

  for (int t = 0; t < TT; ++t) {
    const int p = t & 1;
    const unsigned* xt = a.xu + (size_t)t * BB * 3;
    // Stage B: window(t) on WGs q<32 (+ w-ready flag), proj(t-1) on WGs q>=32.
    // NO group barrier here — LSTM2 gates on the w-ready flags instead.
    if (q < GB) {
      if (isf32) window_stage<true>(a, grp * GB + q, a.h1[1 - p], tid, misc);
      else       window_stage<false>(a, grp * GB + q, a.h1[1 - p], tid, misc);
      __syncthreads();                   // drains all waves' w stores (vmcnt 0)
      if (tid == 0) ast(mya, (unsigned)(t + 1));
    } else if (t > 0) {
      if (isf32) proj_stage<true>(a, t - 1, a.h3[p], grp * GB + q - GB, tid, misc);
      else       proj_stage<false>(a, t - 1, a.h3[p], grp * GB + q - GB, tid, misc);
    }
    // Stage C: LSTM2(t), late-w gate polls the 32 w-ready flags
    gate_mfma_lw(xt, a.wu, a.h1[1 - p], a.h2[p], dz, B2h, B2l,
                 bs2, c2r, a.h2[1 - p], afl, (unsigned)(t + 1), grp, q, zls, tid);
    ++ph; barrier(cnt_grp, ph * 64u, ph + 1u, 64, grp * 64);
    // Stage D: LSTM3(t) on waves 0,1  ||  LSTM1(t+1) on waves 2,3
    gate_mfma<19, true, 0>(xt, a.wu, a.h2[1 - p], a.h3[p], dz, B3h, B3l,
                           bs3, c3r, a.h3[1 - p], grp, q, zls, tid);
    if (t < TT - 1) {
      gate_mfma<11, false, 2>(xt + BB * 3, a.wu, a.h1[1 - p], nullptr, dz,
                              B1h, B1l, bs1, c1r, a.h1[p], grp, q, zls, tid);
    }
    ++ph; barrier(cnt_grp, ph * 64u, ph + 1u, 64, grp * 64);
  }
  if (q >= GB) {
    if (isf32) proj_stage<true>(a, TT - 1, a.h3[0], grp * GB + q - GB, tid, misc);
    else       proj_stage<false>(a, TT - 1, a.h3[0], grp * GB + q - GB, tid, misc);
  }
}

extern "C" void kernel_launch(void* const* d_in, const int* in_sizes, int n_in,
                              void* d_out, int out_size, void* d_ws, size_t ws_size,
                              hipStream_t stream) {
  KArgs a;
  for (int i = 0; i < 27; ++i) a.in[i] = d_in[i];
  a.out = (float*)d_out;

  char* ws = (char*)d_ws;
  size_t off = 0;
  auto take = [&](size_t bytes) {
    void* p = ws + off;
    off = (off + bytes + 127) & ~(size_t)127;
    return p;
  };
  a.kappa = (float*)take(1280 * 4);
  a.wu    = (unsigned*)take(8192 * 4);
  a.h1[0] = (unsigned*)take(32768 * 4);
  a.h1[1] = (unsigned*)take(32768 * 4);
  a.h2[0] = (unsigned*)take(32768 * 4);
  a.h2[1] = (unsigned*)take(32768 * 4);
  a.h3[0] = (unsigned*)take(32768 * 4);
  a.h3[1] = (unsigned*)take(32768 * 4);
  a.xu    = (unsigned*)take(307200 * 4);
  a.bar   = (unsigned*)take(BAR_WORDS * 4);

  bar_init_kernel<<<1, 256, 0, stream>>>(a.bar);
  hsm_kernel<<<NWG, 256, 0, stream>>>(a);
}